// Round 10
// baseline (221.998 us; speedup 1.0000x reference)
//
#include <hip/hip_runtime.h>
#include <cmath>
#include <cstdint>

#define NB 8
#define NPTS 4096
#define NPOINT 204
#define NCENT (NB * NPOINT)   // 1632

typedef unsigned long long u64;

struct BallParams { float thr[5]; int ns[5]; float el; float denom; };
struct FinalParams { double w[5]; };

// ---------------------------------------------------------------------------
// u64 max DPP reduction (champion structure, unchanged): row_shr 1/2/4/8 +
// row_bcast15/31 -> lane 63 holds wave max.
// ---------------------------------------------------------------------------
template<int CTRL, int RMASK>
__device__ __forceinline__ u64 dpp_u64max_step(u64 v) {
    const int lo = (int)(unsigned)v, hi = (int)(unsigned)(v >> 32);
    const int lo2 = __builtin_amdgcn_update_dpp(lo, lo, CTRL, RMASK, 0xF, false);
    const int hi2 = __builtin_amdgcn_update_dpp(hi, hi, CTRL, RMASK, 0xF, false);
    const u64 o = ((u64)(unsigned)hi2 << 32) | (unsigned)lo2;
    return o > v ? o : v;
}
__device__ __forceinline__ u64 wave_u64max63(u64 v) {
    v = dpp_u64max_step<0x111, 0xF>(v);   // row_shr:1
    v = dpp_u64max_step<0x112, 0xF>(v);   // row_shr:2
    v = dpp_u64max_step<0x114, 0xF>(v);   // row_shr:4
    v = dpp_u64max_step<0x118, 0xF>(v);   // row_shr:8
    v = dpp_u64max_step<0x142, 0xA>(v);   // row_bcast:15
    v = dpp_u64max_step<0x143, 0xC>(v);   // row_bcast:31
    return v;                              // lane 63 = wave max
}
__device__ __forceinline__ u64 u64max(u64 a, u64 b) { return a > b ? a : b; }

// Lane-local candidate with coords (register-only cndmask selects).
struct LC { u64 k; float x, y, z; };
__device__ __forceinline__ LC lcmax(LC a, LC b) { return a.k > b.k ? a : b; }

// ---------------------------------------------------------------------------
// Fused: blocks 0..7 FPS (8 waves, 8 pts/lane; winner coords travel through
// the exchange -> NO dependent spts[bi] LDS read on the critical path);
// blocks 8..519 repulsion (R4 structure, untouched).
// ---------------------------------------------------------------------------
__global__ __launch_bounds__(512) void fused_fps_rep(const float* __restrict__ pcd,
                                                     int* __restrict__ fps,
                                                     double* __restrict__ part)
{
#pragma clang fp contract(off)
    __shared__ float4 spts[NPTS];                 // 64 KiB (rep branch only)
    __shared__ int fps_lds[NPOINT];
    __shared__ __align__(16) uint4 exchA[2][8];   // key.lo, key.hi, xbits, ybits
    __shared__ __align__(16) float exchZ[2][8];   // z
    __shared__ double wsum[8];

    const int t = threadIdx.x;
    const int lane = t & 63, wv = t >> 6;

    if (blockIdx.x < NB) {
        // ------------------------------ FPS ------------------------------
        const int b = blockIdx.x;
        const float* base = pcd + (size_t)b * NPTS * 3;

        const int pbase = t * 8;
        float px[8], py[8], pz[8], md[8];
#pragma unroll
        for (int k = 0; k < 8; ++k) {
            px[k] = base[(pbase + k) * 3 + 0];
            py[k] = base[(pbase + k) * 3 + 1];
            pz[k] = base[(pbase + k) * 3 + 2];
            md[k] = 1e10f;
        }
        if (t == 0) fps_lds[0] = 0;

        // first center = point 0 (uniform broadcast load, once)
        float lx = base[0], ly = base[1], lz = base[2];

        for (int it = 1; it < NPOINT; ++it) {
            LC c[8];
            // exact per-element: (dx^2+dy^2)+dz^2, fminf; key = (bits(md)<<32)|(4095-idx)
#pragma unroll
            for (int k = 0; k < 8; ++k) {
                const float dx = px[k] - lx, dy = py[k] - ly, dz = pz[k] - lz;
                float d = dx * dx + dy * dy;
                d = d + dz * dz;
                const float m = fminf(md[k], d);
                md[k] = m;
                c[k].k = ((u64)(unsigned)__float_as_int(m) << 32)
                       | (unsigned)(4095 - (pbase + k));
                c[k].x = px[k]; c[k].y = py[k]; c[k].z = pz[k];
            }
            // lane tree (register-only; coords ride via cndmask)
            c[0] = lcmax(c[0], c[4]); c[1] = lcmax(c[1], c[5]);
            c[2] = lcmax(c[2], c[6]); c[3] = lcmax(c[3], c[7]);
            c[0] = lcmax(c[0], c[2]); c[1] = lcmax(c[1], c[3]);
            c[0] = lcmax(c[0], c[1]);

            // skinny u64 wave chain (identical to champion)
            const u64 wk = wave_u64max63(c[0].k);
            const unsigned klo = (unsigned)__builtin_amdgcn_readlane((int)(unsigned)wk, 63);
            const unsigned khi = (unsigned)__builtin_amdgcn_readlane((int)(unsigned)(wk >> 32), 63);
            const u64 wwk = ((u64)khi << 32) | klo;

            const int p = it & 1;
            // unique winner lane (keys are unique: idx embedded) publishes coords
            if (c[0].k == wwk) {
                exchA[p][wv] = make_uint4(klo, khi,
                                          (unsigned)__float_as_int(c[0].x),
                                          (unsigned)__float_as_int(c[0].y));
                exchZ[p][wv] = c[0].z;
            }
            __syncthreads();

            // block combine: 8 candidates, 3-level key-max with coord selects
            const float4 z03 = ((const float4*)&exchZ[p][0])[0];
            const float4 z47 = ((const float4*)&exchZ[p][0])[1];
            LC a0, a1, a2, a3, a4, a5, a6, a7;
            {
                const uint4 A0 = exchA[p][0], A1 = exchA[p][1];
                const uint4 A2 = exchA[p][2], A3 = exchA[p][3];
                const uint4 A4 = exchA[p][4], A5 = exchA[p][5];
                const uint4 A6 = exchA[p][6], A7 = exchA[p][7];
                a0.k = ((u64)A0.y << 32) | A0.x; a0.x = __int_as_float(A0.z); a0.y = __int_as_float(A0.w); a0.z = z03.x;
                a1.k = ((u64)A1.y << 32) | A1.x; a1.x = __int_as_float(A1.z); a1.y = __int_as_float(A1.w); a1.z = z03.y;
                a2.k = ((u64)A2.y << 32) | A2.x; a2.x = __int_as_float(A2.z); a2.y = __int_as_float(A2.w); a2.z = z03.z;
                a3.k = ((u64)A3.y << 32) | A3.x; a3.x = __int_as_float(A3.z); a3.y = __int_as_float(A3.w); a3.z = z03.w;
                a4.k = ((u64)A4.y << 32) | A4.x; a4.x = __int_as_float(A4.z); a4.y = __int_as_float(A4.w); a4.z = z47.x;
                a5.k = ((u64)A5.y << 32) | A5.x; a5.x = __int_as_float(A5.z); a5.y = __int_as_float(A5.w); a5.z = z47.y;
                a6.k = ((u64)A6.y << 32) | A6.x; a6.x = __int_as_float(A6.z); a6.y = __int_as_float(A6.w); a6.z = z47.z;
                a7.k = ((u64)A7.y << 32) | A7.x; a7.x = __int_as_float(A7.z); a7.y = __int_as_float(A7.w); a7.z = z47.w;
            }
            a0 = lcmax(a0, a1); a2 = lcmax(a2, a3);
            a4 = lcmax(a4, a5); a6 = lcmax(a6, a7);
            a0 = lcmax(a0, a2); a4 = lcmax(a4, a6);
            a0 = lcmax(a0, a4);

            if (t == 0) fps_lds[it] = 4095 - (int)((unsigned)a0.k & 0xFFFu);
            lx = a0.x; ly = a0.y; lz = a0.z;   // no LDS fetch: coords came with the key
        }
        __syncthreads();
        for (int j = t; j < NPOINT; j += 512) fps[b * NPOINT + j] = fps_lds[j];
    } else {
        // --------------------------- repulsion ---------------------------
        const int bb = blockIdx.x - NB;
        const int batch = bb >> 6;
        const int chunk = bb & 63;
        const float* base = pcd + (size_t)batch * NPTS * 3;

        for (int j = t; j < NPTS; j += 512) {
            const float x = base[j * 3 + 0], y = base[j * 3 + 1], z = base[j * 3 + 2];
            const float qs = (x * x + y * y) + z * z;
            spts[j] = make_float4(x, y, z, qs);
        }
        __syncthreads();

        const float h = 0.0005f;
        double acc = 0.0;

        for (int ii = 0; ii < 8; ++ii) {
            const int i = (chunk << 6) + (wv << 3) + ii;
            const float4 C = spts[i];
            const float cx = C.x, cy = C.y, cz = C.z, cs = C.w;
            float s0 = 3e38f, s1 = 3e38f, s2 = 3e38f, s3 = 3e38f;
            for (int bj = 0; bj < NPTS; bj += 64) {
                const int j = bj + lane;
                const float4 o = spts[j];
                const float dot = (cx * o.x + cy * o.y) + cz * o.z;
                const float d = fmaxf((cs + o.w) - 2.0f * dot, 0.0f);
                const bool q = (d < h) && (j != i);
                unsigned long long bal = __ballot(q);
                while (bal) {
                    const int src = __ffsll((unsigned long long)bal) - 1;
                    bal &= bal - 1;
                    const float dv = __shfl(d, src);
                    if (dv < s0) { s3 = s2; s2 = s1; s1 = s0; s0 = dv; }
                    else if (dv < s1) { s3 = s2; s2 = s1; s1 = dv; }
                    else if (dv < s2) { s3 = s2; s2 = dv; }
                    else if (dv < s3) { s3 = dv; }
                }
            }
            if (lane == 0) {
                if (s0 < h) acc += (double)(h - s0);
                if (s1 < h) acc += (double)(h - s1);
                if (s2 < h) acc += (double)(h - s2);
                if (s3 < h) acc += (double)(h - s3);
            }
        }
        if (lane == 0) wsum[wv] = acc;
        __syncthreads();
        if (t == 0) {
            double s = 0.0;
            for (int w = 0; w < 8; ++w) s += wsum[w];
            part[bb] = s;
        }
    }
}

// ---------------------------------------------------------------------------
// Ball query + uniform term, ALL 5 percentages fused into one scan.
// ---------------------------------------------------------------------------
__global__ __launch_bounds__(256) void ball_kernel(const float* __restrict__ pcd,
                                                   const int* __restrict__ fps,
                                                   double* __restrict__ uvals,
                                                   BallParams P)
{
#pragma clang fp contract(off)
    __shared__ float4 spts[NPTS];          // 64 KiB: x,y,z,|q|^2
    __shared__ int wlist[4][5][52];        // per-wave, per-p index lists
    __shared__ float4 gpts[4][64];

    const int wave = threadIdx.x >> 6;
    const int lane = threadIdx.x & 63;
    const int c = blockIdx.x * 4 + wave;   // global center id
    const int b = c / NPOINT;
    const int m = c % NPOINT;

    const float* base = pcd + (size_t)b * NPTS * 3;
    for (int j = threadIdx.x; j < NPTS; j += 256) {
        const float x = base[j * 3 + 0], y = base[j * 3 + 1], z = base[j * 3 + 2];
        const float qs = (x * x + y * y) + z * z;
        spts[j] = make_float4(x, y, z, qs);
    }
    __syncthreads();

    const int ci = fps[b * NPOINT + m];
    const float4 C = spts[ci];
    const float cx = C.x, cy = C.y, cz = C.z, cs = C.w;

    int cnt[5] = {0, 0, 0, 0, 0};
    const u64 lmask = (1ull << lane) - 1ull;
    for (int bj = 0; bj < NPTS; bj += 64) {
        const int j = bj + lane;
        const float4 o = spts[j];
        const float dot = (cx * o.x + cy * o.y) + cz * o.z;
        const float d = fmaxf((cs + o.w) - 2.0f * dot, 0.0f);
#pragma unroll
        for (int p = 0; p < 5; ++p) {
            const bool q = d < P.thr[p];
            const u64 bal = __ballot(q);
            if (q) {
                const int pos = cnt[p] + __popcll(bal & lmask);
                if (pos < P.ns[p]) wlist[wave][p][pos] = j;
            }
            cnt[p] += __popcll(bal);
        }
    }

#pragma unroll
    for (int p = 0; p < 5; ++p) {
        const int nsample = P.ns[p];
        const int m_in = (cnt[p] < nsample) ? cnt[p] : nsample;   // >= 1
        const int gidx = wlist[wave][p][(lane < m_in) ? lane : 0];
        const float4 G = spts[gidx];
        gpts[wave][lane] = G;
        const float gx = G.x, gy = G.y, gz = G.z, gs = G.w;

        float m1 = 3.0e38f, m2 = 3.0e38f;
        for (int j = 0; j < nsample; ++j) {
            const float4 o = gpts[wave][j];
            const float dot = (gx * o.x + gy * o.y) + gz * o.z;
            const float d = fmaxf((gs + o.w) - 2.0f * dot, 0.0f);
            if (d < m1) { m2 = m1; m1 = d; }
            else if (d < m2) { m2 = d; }
        }
        float ud = (lane < nsample) ? fabsf(sqrtf(m2 + 1e-12f) + 1e-8f) : 0.0f;
        for (int off = 32; off; off >>= 1) ud += __shfl_xor(ud, off);
        if (lane == 0) {
            const float um   = ud / (float)nsample;
            const float diff = um - P.el;
            const float u    = (diff * diff) / P.denom;
            uvals[p * NCENT + c] = (double)u;
        }
    }
}

// ---------------------------------------------------------------------------
// Deterministic final reduction + loss assembly (single barrier).
// ---------------------------------------------------------------------------
__global__ __launch_bounds__(256) void final_kernel(const double* __restrict__ uvals,
                                                    const double* __restrict__ part,
                                                    float* __restrict__ out,
                                                    FinalParams F)
{
    __shared__ double red[6][4];
    const int t = threadIdx.x;
    const int lane = t & 63, wv = t >> 6;

    double s[6] = {0.0, 0.0, 0.0, 0.0, 0.0, 0.0};
    for (int c = t; c < NCENT; c += 256) {
        s[0] += uvals[0 * NCENT + c];
        s[1] += uvals[1 * NCENT + c];
        s[2] += uvals[2 * NCENT + c];
        s[3] += uvals[3 * NCENT + c];
        s[4] += uvals[4 * NCENT + c];
    }
    for (int c = t; c < NB * 64; c += 256) s[5] += part[c];

    for (int off = 32; off; off >>= 1) {
#pragma unroll
        for (int p = 0; p < 6; ++p) s[p] += __shfl_xor(s[p], off);
    }
    if (lane == 0) {
#pragma unroll
        for (int p = 0; p < 6; ++p) red[p][wv] = s[p];
    }
    __syncthreads();
    if (t == 0) {
        double sums[6];
#pragma unroll
        for (int p = 0; p < 6; ++p)
            sums[p] = ((red[p][0] + red[p][1]) + red[p][2]) + red[p][3];
        double loss = 0.0;
        loss += (sums[0] / (double)NCENT) * F.w[0];
        loss += (sums[1] / (double)NCENT) * F.w[1];
        loss += (sums[2] / (double)NCENT) * F.w[2];
        loss += (sums[3] / (double)NCENT) * F.w[3];
        loss += (sums[4] / (double)NCENT) * F.w[4];
        loss /= 5.0;
        const double rep = sums[5] / (double)(NB * NPTS * 4);
        out[0] = (float)(loss + rep);
    }
}

// ---------------------------------------------------------------------------
extern "C" void kernel_launch(void* const* d_in, const int* in_sizes, int n_in,
                              void* d_out, int out_size, void* d_ws, size_t ws_size,
                              hipStream_t stream)
{
    const float* pcd = (const float*)d_in[0];
    float* out = (float*)d_out;

    int*    fps   = (int*)d_ws;                                   // NB*NPOINT ints
    double* uvals = (double*)((char*)d_ws + 8192);                // 5*NCENT doubles
    double* repp  = (double*)((char*)d_ws + 8192 + (size_t)5 * NCENT * 8); // NB*64 doubles

    const double pv[5] = {0.004, 0.006, 0.008, 0.01, 0.012};
    const int    nsv[5] = {16, 24, 32, 40, 49};

    BallParams bp;
    FinalParams fp;
    for (int i = 0; i < 5; ++i) {
        const double r = sqrt(pv[i]);
        bp.thr[i] = (float)(r * r);
        bp.ns[i]  = nsv[i];
        const double w = pv[i] * 100.0;
        fp.w[i] = w * w;
    }
    const double el = sqrt(3.141592653589793 / 4096.0);
    bp.el    = (float)el;
    bp.denom = (float)(el + 1e-8);

    fused_fps_rep<<<NB + NB * 64, 512, 0, stream>>>(pcd, fps, repp);
    ball_kernel<<<NCENT / 4, 256, 0, stream>>>(pcd, fps, uvals, bp);
    final_kernel<<<1, 256, 0, stream>>>(uvals, repp, out, fp);
}

// Round 11
// 175.389 us; speedup vs baseline: 1.2658x; 1.2658x over previous
//
#include <hip/hip_runtime.h>
#include <cmath>
#include <cstdint>

#define NB 8
#define NPTS 4096
#define NPOINT 204
#define NCENT (NB * NPOINT)   // 1632

typedef unsigned long long u64;

struct BallParams { float thr[5]; int ns[5]; float el; float denom; };
struct FinalParams { double w[5]; };

// ---------------------------------------------------------------------------
// u64 max DPP reduction: row_shr 1/2/4/8 + row_bcast15/31 -> lane 63 holds max.
// ---------------------------------------------------------------------------
template<int CTRL, int RMASK>
__device__ __forceinline__ u64 dpp_u64max_step(u64 v) {
    const int lo = (int)(unsigned)v, hi = (int)(unsigned)(v >> 32);
    const int lo2 = __builtin_amdgcn_update_dpp(lo, lo, CTRL, RMASK, 0xF, false);
    const int hi2 = __builtin_amdgcn_update_dpp(hi, hi, CTRL, RMASK, 0xF, false);
    const u64 o = ((u64)(unsigned)hi2 << 32) | (unsigned)lo2;
    return o > v ? o : v;
}
__device__ __forceinline__ u64 wave_u64max63(u64 v) {
    v = dpp_u64max_step<0x111, 0xF>(v);   // row_shr:1
    v = dpp_u64max_step<0x112, 0xF>(v);   // row_shr:2
    v = dpp_u64max_step<0x114, 0xF>(v);   // row_shr:4
    v = dpp_u64max_step<0x118, 0xF>(v);   // row_shr:8
    v = dpp_u64max_step<0x142, 0xA>(v);   // row_bcast:15
    v = dpp_u64max_step<0x143, 0xC>(v);   // row_bcast:31
    return v;                              // lane 63 = wave max
}
__device__ __forceinline__ u64 u64max(u64 a, u64 b) { return a > b ? a : b; }

// ---------------------------------------------------------------------------
// Fused (champion R4 structure, verbatim): blocks 0..7 FPS (8 waves, 8
// pts/lane); blocks 8..519 repulsion.
// ---------------------------------------------------------------------------
__global__ __launch_bounds__(512) void fused_fps_rep(const float* __restrict__ pcd,
                                                     int* __restrict__ fps,
                                                     double* __restrict__ part)
{
#pragma clang fp contract(off)
    __shared__ float4 spts[NPTS];                 // 64 KiB
    __shared__ int fps_lds[NPOINT];
    __shared__ __align__(16) u64 exch[2][8];
    __shared__ double wsum[8];

    const int t = threadIdx.x;
    const int lane = t & 63, wv = t >> 6;

    if (blockIdx.x < NB) {
        // ------------------------------ FPS ------------------------------
        const int b = blockIdx.x;
        const float* base = pcd + (size_t)b * NPTS * 3;

        for (int j = t; j < NPTS; j += 512)
            spts[j] = make_float4(base[3*j], base[3*j+1], base[3*j+2], 0.f);

        const int pbase = t * 8;
        float px[8], py[8], pz[8], md[8];
#pragma unroll
        for (int k = 0; k < 8; ++k) {
            px[k] = base[(pbase + k) * 3 + 0];
            py[k] = base[(pbase + k) * 3 + 1];
            pz[k] = base[(pbase + k) * 3 + 2];
            md[k] = 1e10f;
        }
        if (t == 0) fps_lds[0] = 0;
        __syncthreads();

        float lx = spts[0].x, ly = spts[0].y, lz = spts[0].z;

        for (int it = 1; it < NPOINT; ++it) {
            u64 c[8];
            // exact per-element: (dx^2+dy^2)+dz^2, fminf; pack (bits(md)<<32)|(4095-idx)
#pragma unroll
            for (int k = 0; k < 8; ++k) {
                const float dx = px[k] - lx, dy = py[k] - ly, dz = pz[k] - lz;
                float d = dx * dx + dy * dy;
                d = d + dz * dz;
                const float m = fminf(md[k], d);
                md[k] = m;
                c[k] = ((u64)(unsigned)__float_as_int(m) << 32)
                     | (unsigned)(4095 - (pbase + k));
            }
#pragma unroll
            for (int s = 4; s >= 1; s >>= 1)
#pragma unroll
                for (int i = 0; i < 8; ++i)
                    if (i < s) c[i] = u64max(c[i], c[i + s]);
            const u64 wmax = wave_u64max63(c[0]);

            if (lane == 63) exch[it & 1][wv] = wmax;
            __syncthreads();

            const ulonglong2* e = (const ulonglong2*)&exch[it & 1][0];
            const ulonglong2 E0 = e[0], E1 = e[1], E2 = e[2], E3 = e[3];
            u64 m01 = u64max(E0.x, E0.y), m23 = u64max(E1.x, E1.y);
            u64 m45 = u64max(E2.x, E2.y), m67 = u64max(E3.x, E3.y);
            const u64 m = u64max(u64max(m01, m23), u64max(m45, m67));
            const int bi = 4095 - (int)((unsigned)m & 0xFFFu);

            if (t == 0) fps_lds[it] = bi;
            const float4 cc = spts[bi];
            lx = cc.x; ly = cc.y; lz = cc.z;
        }
        __syncthreads();
        for (int j = t; j < NPOINT; j += 512) fps[b * NPOINT + j] = fps_lds[j];
    } else {
        // --------------------------- repulsion ---------------------------
        const int bb = blockIdx.x - NB;
        const int batch = bb >> 6;
        const int chunk = bb & 63;
        const float* base = pcd + (size_t)batch * NPTS * 3;

        for (int j = t; j < NPTS; j += 512) {
            const float x = base[j * 3 + 0], y = base[j * 3 + 1], z = base[j * 3 + 2];
            const float qs = (x * x + y * y) + z * z;
            spts[j] = make_float4(x, y, z, qs);
        }
        __syncthreads();

        const float h = 0.0005f;
        double acc = 0.0;

        for (int ii = 0; ii < 8; ++ii) {
            const int i = (chunk << 6) + (wv << 3) + ii;
            const float4 C = spts[i];
            const float cx = C.x, cy = C.y, cz = C.z, cs = C.w;
            float s0 = 3e38f, s1 = 3e38f, s2 = 3e38f, s3 = 3e38f;
            for (int bj = 0; bj < NPTS; bj += 64) {
                const int j = bj + lane;
                const float4 o = spts[j];
                const float dot = (cx * o.x + cy * o.y) + cz * o.z;
                const float d = fmaxf((cs + o.w) - 2.0f * dot, 0.0f);
                const bool q = (d < h) && (j != i);
                unsigned long long bal = __ballot(q);
                while (bal) {
                    const int src = __ffsll((unsigned long long)bal) - 1;
                    bal &= bal - 1;
                    const float dv = __shfl(d, src);
                    if (dv < s0) { s3 = s2; s2 = s1; s1 = s0; s0 = dv; }
                    else if (dv < s1) { s3 = s2; s2 = s1; s1 = dv; }
                    else if (dv < s2) { s3 = s2; s2 = dv; }
                    else if (dv < s3) { s3 = dv; }
                }
            }
            if (lane == 0) {
                if (s0 < h) acc += (double)(h - s0);
                if (s1 < h) acc += (double)(h - s1);
                if (s2 < h) acc += (double)(h - s2);
                if (s3 < h) acc += (double)(h - s3);
            }
        }
        if (lane == 0) wsum[wv] = acc;
        __syncthreads();
        if (t == 0) {
            double s = 0.0;
            for (int w = 0; w < 8; ++w) s += wsum[w];
            part[bb] = s;
        }
    }
}

// ---------------------------------------------------------------------------
// Ball query + uniform term, 5 p's fused into one scan. Slim LDS: only
// qs[4096] staged (16 KB) -> ~24.5 KB/block -> 6 blocks/CU (24 waves/CU,
// 3x the latency hiding). Coords read from global (L2-hot). Wave-uniform
// early-out on the largest threshold skips the list-update tail ~half the
// j-blocks. Arithmetic bitwise-identical to R9.
// ---------------------------------------------------------------------------
__global__ __launch_bounds__(256) void ball_kernel(const float* __restrict__ pcd,
                                                   const int* __restrict__ fps,
                                                   double* __restrict__ uvals,
                                                   BallParams P)
{
#pragma clang fp contract(off)
    __shared__ float sqs[NPTS];            // 16 KiB: |q|^2, exact op order
    __shared__ int wlist[4][5][52];        // 4.1 KiB
    __shared__ float4 gpts[4][64];         // 4 KiB

    const int wave = threadIdx.x >> 6;
    const int lane = threadIdx.x & 63;
    const int c = blockIdx.x * 4 + wave;   // 204%4==0 -> no batch straddle
    const int b = c / NPOINT;
    const int m = c % NPOINT;

    const float* base = pcd + (size_t)b * NPTS * 3;
    for (int j = threadIdx.x; j < NPTS; j += 256) {
        const float x = base[j * 3 + 0], y = base[j * 3 + 1], z = base[j * 3 + 2];
        sqs[j] = (x * x + y * y) + z * z;
    }
    __syncthreads();

    const int ci = fps[b * NPOINT + m];
    const float cx = base[ci * 3 + 0], cy = base[ci * 3 + 1], cz = base[ci * 3 + 2];
    const float cs = sqs[ci];

    const int ns0 = P.ns[0], ns1 = P.ns[1], ns2 = P.ns[2], ns3 = P.ns[3], ns4 = P.ns[4];
    int cnt[5] = {0, 0, 0, 0, 0};
    const u64 lmask = (1ull << lane) - 1ull;

    for (int bj = 0; bj < NPTS; bj += 64) {
        const int j = bj + lane;
        const float qx = base[j * 3 + 0], qy = base[j * 3 + 1], qz = base[j * 3 + 2];
        const float qs = sqs[j];
        const float dot = (cx * qx + cy * qy) + cz * qz;
        const float d = fmaxf((cs + qs) - 2.0f * dot, 0.0f);

        const u64 bal4 = __ballot(d < P.thr[4]);   // thr[4] largest: gates all
        if (bal4) {
#pragma unroll
            for (int p = 0; p < 4; ++p) {
                const bool q = d < P.thr[p];
                const u64 bal = __ballot(q);
                if (q) {
                    const int pos = cnt[p] + __popcll(bal & lmask);
                    if (pos < P.ns[p]) wlist[wave][p][pos] = j;
                }
                cnt[p] += __popcll(bal);
            }
            if (d < P.thr[4]) {
                const int pos = cnt[4] + __popcll(bal4 & lmask);
                if (pos < ns4) wlist[wave][4][pos] = j;
            }
            cnt[4] += __popcll(bal4);
            if (cnt[0] >= ns0 && cnt[1] >= ns1 && cnt[2] >= ns2 &&
                cnt[3] >= ns3 && cnt[4] >= ns4) break;
        }
    }

#pragma unroll
    for (int p = 0; p < 5; ++p) {
        const int nsample = P.ns[p];
        const int m_in = (cnt[p] < nsample) ? cnt[p] : nsample;   // >= 1 (center inside, d==0)
        const int gidx = wlist[wave][p][(lane < m_in) ? lane : 0];
        const float gx = base[gidx * 3 + 0], gy = base[gidx * 3 + 1], gz = base[gidx * 3 + 2];
        const float gs = sqs[gidx];
        gpts[wave][lane] = make_float4(gx, gy, gz, gs);

        float m1 = 3.0e38f, m2 = 3.0e38f;
        for (int j = 0; j < nsample; ++j) {
            const float4 o = gpts[wave][j];
            const float dot = (gx * o.x + gy * o.y) + gz * o.z;
            const float d = fmaxf((gs + o.w) - 2.0f * dot, 0.0f);
            if (d < m1) { m2 = m1; m1 = d; }
            else if (d < m2) { m2 = d; }
        }
        float ud = (lane < nsample) ? fabsf(sqrtf(m2 + 1e-12f) + 1e-8f) : 0.0f;
        for (int off = 32; off; off >>= 1) ud += __shfl_xor(ud, off);
        if (lane == 0) {
            const float um   = ud / (float)nsample;
            const float diff = um - P.el;
            const float u    = (diff * diff) / P.denom;
            uvals[p * NCENT + c] = (double)u;
        }
    }
}

// ---------------------------------------------------------------------------
// Deterministic final reduction + loss assembly (single barrier).
// ---------------------------------------------------------------------------
__global__ __launch_bounds__(256) void final_kernel(const double* __restrict__ uvals,
                                                    const double* __restrict__ part,
                                                    float* __restrict__ out,
                                                    FinalParams F)
{
    __shared__ double red[6][4];
    const int t = threadIdx.x;
    const int lane = t & 63, wv = t >> 6;

    double s[6] = {0.0, 0.0, 0.0, 0.0, 0.0, 0.0};
    for (int c = t; c < NCENT; c += 256) {
        s[0] += uvals[0 * NCENT + c];
        s[1] += uvals[1 * NCENT + c];
        s[2] += uvals[2 * NCENT + c];
        s[3] += uvals[3 * NCENT + c];
        s[4] += uvals[4 * NCENT + c];
    }
    for (int c = t; c < NB * 64; c += 256) s[5] += part[c];

    for (int off = 32; off; off >>= 1) {
#pragma unroll
        for (int p = 0; p < 6; ++p) s[p] += __shfl_xor(s[p], off);
    }
    if (lane == 0) {
#pragma unroll
        for (int p = 0; p < 6; ++p) red[p][wv] = s[p];
    }
    __syncthreads();
    if (t == 0) {
        double sums[6];
#pragma unroll
        for (int p = 0; p < 6; ++p)
            sums[p] = ((red[p][0] + red[p][1]) + red[p][2]) + red[p][3];
        double loss = 0.0;
        loss += (sums[0] / (double)NCENT) * F.w[0];
        loss += (sums[1] / (double)NCENT) * F.w[1];
        loss += (sums[2] / (double)NCENT) * F.w[2];
        loss += (sums[3] / (double)NCENT) * F.w[3];
        loss += (sums[4] / (double)NCENT) * F.w[4];
        loss /= 5.0;
        const double rep = sums[5] / (double)(NB * NPTS * 4);
        out[0] = (float)(loss + rep);
    }
}

// ---------------------------------------------------------------------------
extern "C" void kernel_launch(void* const* d_in, const int* in_sizes, int n_in,
                              void* d_out, int out_size, void* d_ws, size_t ws_size,
                              hipStream_t stream)
{
    const float* pcd = (const float*)d_in[0];
    float* out = (float*)d_out;

    int*    fps   = (int*)d_ws;                                   // NB*NPOINT ints
    double* uvals = (double*)((char*)d_ws + 8192);                // 5*NCENT doubles
    double* repp  = (double*)((char*)d_ws + 8192 + (size_t)5 * NCENT * 8); // NB*64 doubles

    const double pv[5] = {0.004, 0.006, 0.008, 0.01, 0.012};
    const int    nsv[5] = {16, 24, 32, 40, 49};

    BallParams bp;
    FinalParams fp;
    for (int i = 0; i < 5; ++i) {
        const double r = sqrt(pv[i]);
        bp.thr[i] = (float)(r * r);
        bp.ns[i]  = nsv[i];
        const double w = pv[i] * 100.0;
        fp.w[i] = w * w;
    }
    const double el = sqrt(3.141592653589793 / 4096.0);
    bp.el    = (float)el;
    bp.denom = (float)(el + 1e-8);

    fused_fps_rep<<<NB + NB * 64, 512, 0, stream>>>(pcd, fps, repp);
    ball_kernel<<<NCENT / 4, 256, 0, stream>>>(pcd, fps, uvals, bp);
    final_kernel<<<1, 256, 0, stream>>>(uvals, repp, out, fp);
}

// Round 12
// 159.399 us; speedup vs baseline: 1.3927x; 1.1003x over previous
//
#include <hip/hip_runtime.h>
#include <cmath>
#include <cstdint>

#define NB 8
#define NPTS 4096
#define NPOINT 204
#define NCENT (NB * NPOINT)   // 1632

typedef unsigned long long u64;

struct BallParams { float thr[5]; int ns[5]; float el; float denom; };
struct FinalParams { double w[5]; };

// ---------------------------------------------------------------------------
// u64 max DPP reduction: row_shr 1/2/4/8 + row_bcast15/31 -> lane 63 holds max.
// ---------------------------------------------------------------------------
template<int CTRL, int RMASK>
__device__ __forceinline__ u64 dpp_u64max_step(u64 v) {
    const int lo = (int)(unsigned)v, hi = (int)(unsigned)(v >> 32);
    const int lo2 = __builtin_amdgcn_update_dpp(lo, lo, CTRL, RMASK, 0xF, false);
    const int hi2 = __builtin_amdgcn_update_dpp(hi, hi, CTRL, RMASK, 0xF, false);
    const u64 o = ((u64)(unsigned)hi2 << 32) | (unsigned)lo2;
    return o > v ? o : v;
}
__device__ __forceinline__ u64 wave_u64max63(u64 v) {
    v = dpp_u64max_step<0x111, 0xF>(v);   // row_shr:1
    v = dpp_u64max_step<0x112, 0xF>(v);   // row_shr:2
    v = dpp_u64max_step<0x114, 0xF>(v);   // row_shr:4
    v = dpp_u64max_step<0x118, 0xF>(v);   // row_shr:8
    v = dpp_u64max_step<0x142, 0xA>(v);   // row_bcast:15
    v = dpp_u64max_step<0x143, 0xC>(v);   // row_bcast:31
    return v;                              // lane 63 = wave max
}
__device__ __forceinline__ u64 u64max(u64 a, u64 b) { return a > b ? a : b; }

// ---------------------------------------------------------------------------
// Fused (champion R4 structure, verbatim): blocks 0..7 FPS (8 waves, 8
// pts/lane); blocks 8..519 repulsion.
// ---------------------------------------------------------------------------
__global__ __launch_bounds__(512) void fused_fps_rep(const float* __restrict__ pcd,
                                                     int* __restrict__ fps,
                                                     double* __restrict__ part)
{
#pragma clang fp contract(off)
    __shared__ float4 spts[NPTS];                 // 64 KiB
    __shared__ int fps_lds[NPOINT];
    __shared__ __align__(16) u64 exch[2][8];
    __shared__ double wsum[8];

    const int t = threadIdx.x;
    const int lane = t & 63, wv = t >> 6;

    if (blockIdx.x < NB) {
        // ------------------------------ FPS ------------------------------
        const int b = blockIdx.x;
        const float* base = pcd + (size_t)b * NPTS * 3;

        for (int j = t; j < NPTS; j += 512)
            spts[j] = make_float4(base[3*j], base[3*j+1], base[3*j+2], 0.f);

        const int pbase = t * 8;
        float px[8], py[8], pz[8], md[8];
#pragma unroll
        for (int k = 0; k < 8; ++k) {
            px[k] = base[(pbase + k) * 3 + 0];
            py[k] = base[(pbase + k) * 3 + 1];
            pz[k] = base[(pbase + k) * 3 + 2];
            md[k] = 1e10f;
        }
        if (t == 0) fps_lds[0] = 0;
        __syncthreads();

        float lx = spts[0].x, ly = spts[0].y, lz = spts[0].z;

        for (int it = 1; it < NPOINT; ++it) {
            u64 c[8];
            // exact per-element: (dx^2+dy^2)+dz^2, fminf; pack (bits(md)<<32)|(4095-idx)
#pragma unroll
            for (int k = 0; k < 8; ++k) {
                const float dx = px[k] - lx, dy = py[k] - ly, dz = pz[k] - lz;
                float d = dx * dx + dy * dy;
                d = d + dz * dz;
                const float m = fminf(md[k], d);
                md[k] = m;
                c[k] = ((u64)(unsigned)__float_as_int(m) << 32)
                     | (unsigned)(4095 - (pbase + k));
            }
#pragma unroll
            for (int s = 4; s >= 1; s >>= 1)
#pragma unroll
                for (int i = 0; i < 8; ++i)
                    if (i < s) c[i] = u64max(c[i], c[i + s]);
            const u64 wmax = wave_u64max63(c[0]);

            if (lane == 63) exch[it & 1][wv] = wmax;
            __syncthreads();

            const ulonglong2* e = (const ulonglong2*)&exch[it & 1][0];
            const ulonglong2 E0 = e[0], E1 = e[1], E2 = e[2], E3 = e[3];
            u64 m01 = u64max(E0.x, E0.y), m23 = u64max(E1.x, E1.y);
            u64 m45 = u64max(E2.x, E2.y), m67 = u64max(E3.x, E3.y);
            const u64 m = u64max(u64max(m01, m23), u64max(m45, m67));
            const int bi = 4095 - (int)((unsigned)m & 0xFFFu);

            if (t == 0) fps_lds[it] = bi;
            const float4 cc = spts[bi];
            lx = cc.x; ly = cc.y; lz = cc.z;
        }
        __syncthreads();
        for (int j = t; j < NPOINT; j += 512) fps[b * NPOINT + j] = fps_lds[j];
    } else {
        // --------------------------- repulsion ---------------------------
        const int bb = blockIdx.x - NB;
        const int batch = bb >> 6;
        const int chunk = bb & 63;
        const float* base = pcd + (size_t)batch * NPTS * 3;

        for (int j = t; j < NPTS; j += 512) {
            const float x = base[j * 3 + 0], y = base[j * 3 + 1], z = base[j * 3 + 2];
            const float qs = (x * x + y * y) + z * z;
            spts[j] = make_float4(x, y, z, qs);
        }
        __syncthreads();

        const float h = 0.0005f;
        double acc = 0.0;

        for (int ii = 0; ii < 8; ++ii) {
            const int i = (chunk << 6) + (wv << 3) + ii;
            const float4 C = spts[i];
            const float cx = C.x, cy = C.y, cz = C.z, cs = C.w;
            float s0 = 3e38f, s1 = 3e38f, s2 = 3e38f, s3 = 3e38f;
            for (int bj = 0; bj < NPTS; bj += 64) {
                const int j = bj + lane;
                const float4 o = spts[j];
                const float dot = (cx * o.x + cy * o.y) + cz * o.z;
                const float d = fmaxf((cs + o.w) - 2.0f * dot, 0.0f);
                const bool q = (d < h) && (j != i);
                unsigned long long bal = __ballot(q);
                while (bal) {
                    const int src = __ffsll((unsigned long long)bal) - 1;
                    bal &= bal - 1;
                    const float dv = __shfl(d, src);
                    if (dv < s0) { s3 = s2; s2 = s1; s1 = s0; s0 = dv; }
                    else if (dv < s1) { s3 = s2; s2 = s1; s1 = dv; }
                    else if (dv < s2) { s3 = s2; s2 = dv; }
                    else if (dv < s3) { s3 = dv; }
                }
            }
            if (lane == 0) {
                if (s0 < h) acc += (double)(h - s0);
                if (s1 < h) acc += (double)(h - s1);
                if (s2 < h) acc += (double)(h - s2);
                if (s3 < h) acc += (double)(h - s3);
            }
        }
        if (lane == 0) wsum[wv] = acc;
        __syncthreads();
        if (t == 0) {
            double s = 0.0;
            for (int w = 0; w < 8; ++w) s += wsum[w];
            part[bb] = s;
        }
    }
}

// ---------------------------------------------------------------------------
// Ball query + uniform term: ONE BLOCK PER CENTER, cooperative 4-wave scan.
// Wave w scans j in [w*1024,(w+1)*1024); per-wave compacted lists concatenate
// (in wave order) to the exact ascending-index reference list. Group phases
// distributed across waves (w0:p4, w1:p3, w2:p2, w3:p0,p1).
// ---------------------------------------------------------------------------
__global__ __launch_bounds__(256) void ball_kernel(const float* __restrict__ pcd,
                                                   const int* __restrict__ fps,
                                                   double* __restrict__ uvals,
                                                   BallParams P)
{
#pragma clang fp contract(off)
    __shared__ int wlist[4][5][52];        // per-wave partial lists
    __shared__ int scnt[4][5];             // per-wave qualifier counts
    __shared__ float4 gpts[4][64];         // per-wave group stage

    const int wave = threadIdx.x >> 6;
    const int lane = threadIdx.x & 63;
    const int c = blockIdx.x;              // one center per block
    const int b = c / NPOINT;
    const int m = c % NPOINT;

    const float* base = pcd + (size_t)b * NPTS * 3;
    const int ci = fps[b * NPOINT + m];
    const float cx = base[ci * 3 + 0], cy = base[ci * 3 + 1], cz = base[ci * 3 + 2];
    const float cs = (cx * cx + cy * cy) + cz * cz;

    int cnt[5] = {0, 0, 0, 0, 0};
    const u64 lmask = (1ull << lane) - 1ull;

    // wave-private scan of 1024 points (16 j-blocks)
    const int j0 = wave << 10;
    for (int bj = 0; bj < 1024; bj += 64) {
        const int j = j0 + bj + lane;
        const float qx = base[j * 3 + 0], qy = base[j * 3 + 1], qz = base[j * 3 + 2];
        const float qs = (qx * qx + qy * qy) + qz * qz;
        const float dot = (cx * qx + cy * qy) + cz * qz;
        const float d = fmaxf((cs + qs) - 2.0f * dot, 0.0f);

        const u64 bal4 = __ballot(d < P.thr[4]);   // largest thr gates all
        if (bal4) {
#pragma unroll
            for (int p = 0; p < 4; ++p) {
                const bool q = d < P.thr[p];
                const u64 bal = __ballot(q);
                if (q) {
                    const int pos = cnt[p] + __popcll(bal & lmask);
                    if (pos < P.ns[p]) wlist[wave][p][pos] = j;
                }
                cnt[p] += __popcll(bal);
            }
            if (d < P.thr[4]) {
                const int pos = cnt[4] + __popcll(bal4 & lmask);
                if (pos < P.ns[4]) wlist[wave][4][pos] = j;
            }
            cnt[4] += __popcll(bal4);
        }
    }
    if (lane == 0) {
#pragma unroll
        for (int p = 0; p < 5; ++p) scnt[wave][p] = cnt[p];
    }
    __syncthreads();

    // group phases distributed: wave0->p4, wave1->p3, wave2->p2, wave3->p0,p1
    const int np_of[4]  = {1, 1, 1, 2};
    const int p0_of[4]  = {4, 3, 2, 0};
    for (int pi = 0; pi < np_of[wave]; ++pi) {
        const int p = p0_of[wave] + pi;
        const int nsample = P.ns[p];
        const int n0 = scnt[0][p], n1 = scnt[1][p], n2 = scnt[2][p], n3 = scnt[3][p];
        const int total = ((n0 + n1) + n2) + n3;
        const int m_in = (total < nsample) ? total : nsample;     // >= 1 (center inside)

        // lane-parallel 4-way merge: global position -> (src wave, local idx)
        auto src_of = [&](int pos) -> int {
            int w = 0, q = pos;
            if (q >= n0) { q -= n0; w = 1;
                if (q >= n1) { q -= n1; w = 2;
                    if (q >= n2) { q -= n2; w = 3; } } }
            return wlist[w][p][q];
        };
        const int gidx = src_of((lane < m_in) ? lane : 0);
        const float gx = base[gidx * 3 + 0], gy = base[gidx * 3 + 1], gz = base[gidx * 3 + 2];
        const float gs = (gx * gx + gy * gy) + gz * gz;
        gpts[wave][lane] = make_float4(gx, gy, gz, gs);

        float m1 = 3.0e38f, m2 = 3.0e38f;
        for (int j = 0; j < nsample; ++j) {
            const float4 o = gpts[wave][j];
            const float dot = (gx * o.x + gy * o.y) + gz * o.z;
            const float d = fmaxf((gs + o.w) - 2.0f * dot, 0.0f);
            if (d < m1) { m2 = m1; m1 = d; }
            else if (d < m2) { m2 = d; }
        }
        float ud = (lane < nsample) ? fabsf(sqrtf(m2 + 1e-12f) + 1e-8f) : 0.0f;
        for (int off = 32; off; off >>= 1) ud += __shfl_xor(ud, off);
        if (lane == 0) {
            const float um   = ud / (float)nsample;
            const float diff = um - P.el;
            const float u    = (diff * diff) / P.denom;
            uvals[p * NCENT + c] = (double)u;
        }
    }
}

// ---------------------------------------------------------------------------
// Deterministic final reduction + loss assembly (single barrier).
// ---------------------------------------------------------------------------
__global__ __launch_bounds__(256) void final_kernel(const double* __restrict__ uvals,
                                                    const double* __restrict__ part,
                                                    float* __restrict__ out,
                                                    FinalParams F)
{
    __shared__ double red[6][4];
    const int t = threadIdx.x;
    const int lane = t & 63, wv = t >> 6;

    double s[6] = {0.0, 0.0, 0.0, 0.0, 0.0, 0.0};
    for (int c = t; c < NCENT; c += 256) {
        s[0] += uvals[0 * NCENT + c];
        s[1] += uvals[1 * NCENT + c];
        s[2] += uvals[2 * NCENT + c];
        s[3] += uvals[3 * NCENT + c];
        s[4] += uvals[4 * NCENT + c];
    }
    for (int c = t; c < NB * 64; c += 256) s[5] += part[c];

    for (int off = 32; off; off >>= 1) {
#pragma unroll
        for (int p = 0; p < 6; ++p) s[p] += __shfl_xor(s[p], off);
    }
    if (lane == 0) {
#pragma unroll
        for (int p = 0; p < 6; ++p) red[p][wv] = s[p];
    }
    __syncthreads();
    if (t == 0) {
        double sums[6];
#pragma unroll
        for (int p = 0; p < 6; ++p)
            sums[p] = ((red[p][0] + red[p][1]) + red[p][2]) + red[p][3];
        double loss = 0.0;
        loss += (sums[0] / (double)NCENT) * F.w[0];
        loss += (sums[1] / (double)NCENT) * F.w[1];
        loss += (sums[2] / (double)NCENT) * F.w[2];
        loss += (sums[3] / (double)NCENT) * F.w[3];
        loss += (sums[4] / (double)NCENT) * F.w[4];
        loss /= 5.0;
        const double rep = sums[5] / (double)(NB * NPTS * 4);
        out[0] = (float)(loss + rep);
    }
}

// ---------------------------------------------------------------------------
extern "C" void kernel_launch(void* const* d_in, const int* in_sizes, int n_in,
                              void* d_out, int out_size, void* d_ws, size_t ws_size,
                              hipStream_t stream)
{
    const float* pcd = (const float*)d_in[0];
    float* out = (float*)d_out;

    int*    fps   = (int*)d_ws;                                   // NB*NPOINT ints
    double* uvals = (double*)((char*)d_ws + 8192);                // 5*NCENT doubles
    double* repp  = (double*)((char*)d_ws + 8192 + (size_t)5 * NCENT * 8); // NB*64 doubles

    const double pv[5] = {0.004, 0.006, 0.008, 0.01, 0.012};
    const int    nsv[5] = {16, 24, 32, 40, 49};

    BallParams bp;
    FinalParams fp;
    for (int i = 0; i < 5; ++i) {
        const double r = sqrt(pv[i]);
        bp.thr[i] = (float)(r * r);
        bp.ns[i]  = nsv[i];
        const double w = pv[i] * 100.0;
        fp.w[i] = w * w;
    }
    const double el = sqrt(3.141592653589793 / 4096.0);
    bp.el    = (float)el;
    bp.denom = (float)(el + 1e-8);

    fused_fps_rep<<<NB + NB * 64, 512, 0, stream>>>(pcd, fps, repp);
    ball_kernel<<<NCENT, 256, 0, stream>>>(pcd, fps, uvals, bp);
    final_kernel<<<1, 256, 0, stream>>>(uvals, repp, out, fp);
}